// Round 15
// baseline (432.253 us; speedup 1.0000x reference)
//
#include <hip/hip_runtime.h>

// LSTM B=4096, T=512, I=1, H=64, O=1 (fp32 in/out).
// Round 15: SINGLE-WAVE RECURRENCE — barrier count ZERO.
// Block = 64 thr (1 wave) owns MB=4 batches end-to-end; grid = 1024
// (4 waves/CU, 1/SIMD). The wave computes all 256 gate rows itself:
// 16 N-tiles x 2 K-chunks = 32 MFMA/step. h lives in block-local LDS;
// intra-wave RAW ordering is just lgkmcnt (compiler-inserted) -> no
// __syncthreads, no ping-pong. 14 rounds showed every cross-wave h exchange
// pays ~500+ cyc/step of barrier chain; this removes it structurally.
// M layout (16 rows): row 2q = h[batch q] (fp16), odd rows = 0,
// rows 8+2q = DUPLICATE of batch q  -> every lane's D rows are valid:
// lane (l16,h0): batches qb=2(h0&1)+{0,1} at acc elements 0,2;
// units u = (h0>>1)*32 + {l16, 16+l16} via tiles kb+{0,1}, kb=2(h0>>1)
// (one f32x2 cndmask-select per gate vector). 4 cells/lane, 24 trans
// (r13 pair-shared rcp), pk-f32 cell math (r14), exp2-prescaled weights,
// x*w_ih+bias as MFMA C operand.
// MFMA layouts (m89-verified): A[m=lane&15][k=(lane>>4)*8+i],
// B[k=(lane>>4)*8+i][n=lane&15], D[m=(lane>>4)*4+r][n=lane&15].

#define TT  512
#define HP  72             // f16 row stride (144 B): 16B-aligned
#define SXQ 4              // sh_x row stride (floats)

#define L2E  1.4426950408889634f
#define L2E2 2.8853900817779268f

typedef _Float16 f16x8 __attribute__((ext_vector_type(8)));
typedef float    f32x4 __attribute__((ext_vector_type(4)));
typedef float    f32x2 __attribute__((ext_vector_type(2)));

#define MFMA16(a, b, c) __builtin_amdgcn_mfma_f32_16x16x32_f16((a), (b), (c), 0, 0, 0)

__device__ __forceinline__ float rcp_(float x)  { return __builtin_amdgcn_rcpf(x); }
__device__ __forceinline__ float exp2_(float x) { return __builtin_amdgcn_exp2f(x); }

__device__ __forceinline__ f16x8 cvt8s(const float4& u0, const float4& u1, float s) {
    f16x8 r;
    r[0] = (_Float16)(u0.x * s); r[1] = (_Float16)(u0.y * s);
    r[2] = (_Float16)(u0.z * s); r[3] = (_Float16)(u0.w * s);
    r[4] = (_Float16)(u1.x * s); r[5] = (_Float16)(u1.y * s);
    r[6] = (_Float16)(u1.z * s); r[7] = (_Float16)(u1.w * s);
    return r;
}

__global__ __launch_bounds__(64, 1) void lstm_sw(
    const float* __restrict__ x,      // [4096, 512]
    const float* __restrict__ w_ih,   // [256]
    const float* __restrict__ w_hh,   // [256, 64]
    const float* __restrict__ b_ih,   // [256]
    const float* __restrict__ b_hh,   // [256]
    const float* __restrict__ w_out,  // [64]
    const float* __restrict__ b_out,  // [1]
    float* __restrict__ out)          // [4096]
{
    __shared__ __align__(16) float    sh_x[TT * SXQ];  // [t][batch], 8 KB
    __shared__ __align__(16) _Float16 hb[16 * HP];     // h rows, 2.25 KB

    const int L   = threadIdx.x;      // 0..63 (single wave)
    const int l16 = L & 15;
    const int h0  = L >> 4;           // 0..3
    const int b0  = blockIdx.x * 4;

    // ---- stage x: sh_x[t*SXQ + q] = x[b0+q][t] (float4 coalesced) ----
    #pragma unroll
    for (int q = 0; q < 4; ++q) {
        const float* xr = x + (size_t)(b0 + q) * TT;
        #pragma unroll
        for (int i = 0; i < 2; ++i) {
            const int t0 = 4 * (L + 64 * i);
            float4 v = *(const float4*)(xr + t0);
            sh_x[(t0 + 0) * SXQ + q] = v.x;
            sh_x[(t0 + 1) * SXQ + q] = v.y;
            sh_x[(t0 + 2) * SXQ + q] = v.z;
            sh_x[(t0 + 3) * SXQ + q] = v.w;
        }
    }
    // ---- zero h rows (odd rows stay zero forever) ----
    #pragma unroll
    for (int i = L; i < 16 * HP; i += 64) hb[i] = (_Float16)0.0f;

    // ---- weights: 16 tiles, fp16-rounded + exp2-prescaled ----
    const float sc[4] = {-L2E, -L2E, L2E2, -L2E};
    f16x8 Bf[16][2];
    float wihv[16], biasv[16];
    #pragma unroll
    for (int p = 0; p < 16; ++p) {
        const int n = 16 * p + l16;       // gate row this lane's B-col covers
        const float s = sc[p >> 2];
        #pragma unroll
        for (int c = 0; c < 2; ++c) {
            const float* w0 = w_hh + n * 64 + 32 * c + 8 * h0;
            float4 u0 = *(const float4*)w0;
            float4 u1 = *(const float4*)(w0 + 4);
            Bf[p][c] = cvt8s(u0, u1, s);
        }
        wihv[p]  = w_ih[n] * s;
        biasv[p] = (b_ih[n] + b_hh[n]) * s;
    }

    const int  qb   = 2 * (h0 & 1);          // lane's batches: qb, qb+1
    const bool hi   = (h0 >> 1) != 0;        // unit half: tiles {2,3} vs {0,1}
    const int  aoff = l16 * HP + 8 * h0;     // A-frag base (f16); +32 chunk 1
    const int  uc   = (hi ? 32 : 0) + l16;   // col of unit kappa=0 (+16 for k=1)
    const int  wr0  = (2 * qb) * HP;         // batch qb row (dup at +8*HP)
    const int  wr1  = (2 * qb + 2) * HP;     // batch qb+1 row

    f32x2 cca = {0.0f, 0.0f};   // c of cells (u, qb), (u+16, qb)
    f32x2 ccb = {0.0f, 0.0f};   // c of cells (u, qb+1), (u+16, qb+1)

    // pk dual-cell update (r13 pair-shared rcp, r14 packed math)
    auto pair_up = [&](f32x2 ai, f32x2 af, f32x2 ag, f32x2 ao, f32x2& cc) -> f32x2 {
        f32x2 Ei = {exp2_(ai[0]), exp2_(ai[1])};
        f32x2 Ef = {exp2_(af[0]), exp2_(af[1])};
        f32x2 Eg = {exp2_(ag[0]), exp2_(ag[1])};
        f32x2 Eo = {exp2_(ao[0]), exp2_(ao[1])};
        f32x2 Di = Ei + 1.0f, Df = Ef + 1.0f, Dg = Eg + 1.0f, Do = Eo + 1.0f;
        f32x2 FG = Df * Dg, IG = Di * Dg, IF = Di * Df;
        f32x2 P  = Di * FG;
        float u  = rcp_(P[0] * P[1]);
        f32x2 inv = {u * P[1], u * P[0]};
        f32x2 si = FG * inv, sf = IG * inv;
        f32x2 tg = 1.0f - 2.0f * (IF * inv);
        cc = sf * cc + si * tg;
        f32x2 ca = cc * L2E2;
        f32x2 Ec = {exp2_(fminf(ca[0], 30.0f)), exp2_(fminf(ca[1], 30.0f))};
        f32x2 Dc = Ec + 1.0f;
        f32x2 Q  = Do * Dc;
        float v  = rcp_(Q[0] * Q[1]);
        f32x2 iq = {v * Q[1], v * Q[0]};
        return (iq * Dc) * (1.0f - 2.0f * (iq * Do));
    };

    for (int t = 0; t < TT; ++t) {
        f16x8 A0 = *(const f16x8*)(hb + aoff);
        f16x8 A1 = *(const f16x8*)(hb + aoff + 32);
        const float2 xv = *(const float2*)(sh_x + SXQ * t + qb);
        const float cx0 = xv.x, cx1 = xv.y;

        f32x4 acc[16];
        #pragma unroll
        for (int p = 0; p < 16; ++p) {
            f32x4 c0 = {fmaf(cx0, wihv[p], biasv[p]), 0.0f,
                        fmaf(cx1, wihv[p], biasv[p]), 0.0f};
            acc[p] = MFMA16(A1, Bf[p][1], MFMA16(A0, Bf[p][0], c0));
        }

        // gate vectors: elements = units (u, u+16); tile-half select on `hi`
        #define GS(tau, e) (hi ? (f32x2){acc[4*(tau)+2][e], acc[4*(tau)+3][e]} \
                               : (f32x2){acc[4*(tau)+0][e], acc[4*(tau)+1][e]})
        f32x2 Ai0 = GS(0, 0), Af0 = GS(1, 0), Ag0 = GS(2, 0), Ao0 = GS(3, 0);
        f32x2 Ai1 = GS(0, 2), Af1 = GS(1, 2), Ag1 = GS(2, 2), Ao1 = GS(3, 2);
        #undef GS

        f32x2 hva = pair_up(Ai0, Af0, Ag0, Ao0, cca);   // batch qb
        f32x2 hvb = pair_up(Ai1, Af1, Ag1, Ao1, ccb);   // batch qb+1

        // h writes: real row + duplicate row (+8*HP), 2 units each
        _Float16 a0 = (_Float16)hva[0], a1 = (_Float16)hva[1];
        _Float16 b0h = (_Float16)hvb[0], b1h = (_Float16)hvb[1];
        hb[wr0 + uc]               = a0;
        hb[wr0 + uc + 16]          = a1;
        hb[wr0 + 8 * HP + uc]      = a0;
        hb[wr0 + 8 * HP + uc + 16] = a1;
        hb[wr1 + uc]               = b0h;
        hb[wr1 + uc + 16]          = b1h;
        hb[wr1 + 8 * HP + uc]      = b0h;
        hb[wr1 + 8 * HP + uc + 16] = b1h;
        // no barrier: single wave, LDS RAW ordered by lgkmcnt
    }

    // ---- epilogue: out[b0+q] = h[q] . w_out + b_out ----
    const float wo = w_out[L];
    #pragma unroll
    for (int q = 0; q < 4; ++q) {
        float v = (float)hb[(2 * q) * HP + L] * wo;
        #pragma unroll
        for (int off = 32; off; off >>= 1) v += __shfl_down(v, off);
        if (L == 0) out[b0 + q] = v + b_out[0];
    }
}

extern "C" void kernel_launch(void* const* d_in, const int* in_sizes, int n_in,
                              void* d_out, int out_size, void* d_ws, size_t ws_size,
                              hipStream_t stream) {
    const float* x     = (const float*)d_in[0];
    const float* w_ih  = (const float*)d_in[1];
    const float* w_hh  = (const float*)d_in[2];
    const float* b_ih  = (const float*)d_in[3];
    const float* b_hh  = (const float*)d_in[4];
    const float* w_out = (const float*)d_in[5];
    const float* b_out = (const float*)d_in[6];
    float* out = (float*)d_out;

    lstm_sw<<<1024, 64, 0, stream>>>(x, w_ih, w_hh, b_ih, b_hh,
                                     w_out, b_out, out);
}